// Round 5
// baseline (365.567 us; speedup 1.0000x reference)
//
#include <hip/hip_runtime.h>
#include <hip/hip_bf16.h>

typedef __attribute__((ext_vector_type(8))) short short8;
typedef __attribute__((ext_vector_type(4))) float f32x4;
typedef unsigned short u16;

#define DEV static __device__ __forceinline__

constexpr int Bsz = 4, Tn = 2048, Cn = 1024, Hn = 16, Dn = 64;
constexpr int TP = Tn + 32;  // padded VT row stride: 4160B, breaks 4KB channel aliasing
constexpr int VROWS = 80;    // 64 d-rows + row64=ones (l-column) + 15 zero rows
// QK^T scale folded into Q in the GEMM epilogue: 0.125 * log2(e); softmax in exp2 domain.
#define QSCL 0.1803368801111204f

DEV u16 f2bf(float f) {  // round-to-nearest (ties away): 2 VALU
    union { float f; unsigned u; } v{f};
    return (u16)((v.u + 0x8000u) >> 16);
}
DEV float bf2f(u16 u) {
    union { unsigned u; float f; } v;
    v.u = ((unsigned)u) << 16;
    return v.f;
}

DEV void gload_lds16(const void* g, void* l) {
    __builtin_amdgcn_global_load_lds((const __attribute__((address_space(1))) void*)g,
                                     (__attribute__((address_space(3))) void*)l, 16, 0, 0);
}

// ---------------- fp32 -> bf16 convert (vectorized) ----------------
__global__ void cvt_kernel(const float* __restrict__ in, u16* __restrict__ out, int n4) {
    int i = blockIdx.x * blockDim.x + threadIdx.x;
    int stride = gridDim.x * blockDim.x;
    for (; i < n4; i += stride) {
        float4 v = ((const float4*)in)[i];
        short4 o;
        o.x = (short)f2bf(v.x); o.y = (short)f2bf(v.y);
        o.z = (short)f2bf(v.z); o.w = (short)f2bf(v.w);
        ((short4*)out)[i] = o;
    }
}

// ---------------- 4 weight matrices in one launch ----------------
__global__ void cvtw_kernel(const float* __restrict__ w0, const float* __restrict__ w1,
                            const float* __restrict__ w2, const float* __restrict__ w3,
                            u16* o0, u16* o1, u16* o2, u16* o3) {
    const float* src = blockIdx.y == 0 ? w0 : blockIdx.y == 1 ? w1 : blockIdx.y == 2 ? w2 : w3;
    u16* dst = blockIdx.y == 0 ? o0 : blockIdx.y == 1 ? o1 : blockIdx.y == 2 ? o2 : o3;
    int i = blockIdx.x * blockDim.x + threadIdx.x;
    float4 v = ((const float4*)src)[i];
    short4 o;
    o.x = (short)f2bf(v.x); o.y = (short)f2bf(v.y);
    o.z = (short)f2bf(v.z); o.w = (short)f2bf(v.w);
    ((short4*)dst)[i] = o;
}

// ---------------- RoPE trig tables [T][32] ----------------
__global__ void trig_kernel(float* __restrict__ cs, float* __restrict__ sn) {
    int idx = blockIdx.x * blockDim.x + threadIdx.x; // Tn*32
    int t = idx >> 5, i = idx & 31;
    double inv = pow(10000.0, -(double)i / 32.0);
    double a = (double)t * inv;
    cs[idx] = (float)cos(a);
    sn[idx] = (float)sin(a);
}

// rows 64..79 of each VT head: row 64 = 1.0 (l-column), rows 65..79 = 0
__global__ void fill_ones(u16* __restrict__ vt) {
    long idx = (long)blockIdx.x * 256 + threadIdx.x; // 64*16*TP total
    long bh = idx / (16 * TP);
    long rem = idx % (16 * TP);
    long r = rem / TP, t = rem % TP;
    vt[(bh * VROWS + 64 + r) * TP + t] = (r == 0) ? (u16)0x3f80 : (u16)0;
}

// ---------------- 128x128 bf16 GEMM, C = A * B^T ----------------
// MODE 0: QK projections. grid.z in {0,1} selects (B0->O0)=Q / (B1->O1)=K.
//         Epilogue applies RoPE (thread-local: d and d+32 are acc[i][j], acc[i][j+2])
//         and QSCL for Q; writes bf16 [B,H,T,D].
// MODE 1: fp32 row-major [M,N] (output projection).
// MODE 2: V^T producer: A=wv, B=x -> C[c_out][bt]; writes bf16 vt[bh][d][t] (TP stride).
template <int MODE>
__global__ __launch_bounds__(256, 2) void gemm_bt(
    const u16* __restrict__ A,
    const u16* __restrict__ B0, const u16* __restrict__ B1,
    void* __restrict__ O0, void* __restrict__ O1,
    const float* __restrict__ CS, const float* __restrict__ SN,
    int M, int N, int K) {
    __shared__ u16 As[128 * 32];
    __shared__ u16 Bs[128 * 32];

    const u16* Bp = B0;
    void* Op = O0;
    float scl = 1.0f;
    if (MODE == 0) {
        if (blockIdx.z == 1) { Bp = B1; Op = O1; }
        else scl = QSCL;
    }
    int tid = threadIdx.x;
    int w = tid >> 6, lane = tid & 63;
    int lr = lane & 15, lg = lane >> 4;
    int wr = w >> 1, wc = w & 1;
    long brow = (long)blockIdx.x * 128, bcol = (long)blockIdx.y * 128;

    f32x4 acc[4][4] = {};
    const u16* Arow = A + brow * K;
    const u16* Brow = Bp + bcol * K;

    for (int k0 = 0; k0 < K; k0 += 32) {
        __syncthreads();
#pragma unroll
        for (int c = 0; c < 2; c++) {
            int idx = c * 256 + tid;
            int row = idx >> 2, col = (idx & 3) << 3;
            const u16* ga = Arow + (long)row * K + k0 + col;
            const u16* gb = Brow + (long)row * K + k0 + col;
            char* la = (char*)As + (size_t)(c * 256 + (tid & 192)) * 16;
            char* lb = (char*)Bs + (size_t)(c * 256 + (tid & 192)) * 16;
            gload_lds16(ga, la);
            gload_lds16(gb, lb);
        }
        __syncthreads();
        short8 a[4], b[4];
#pragma unroll
        for (int i = 0; i < 4; i++)
            a[i] = *(const short8*)&As[(64 * wr + 16 * i + lr) * 32 + lg * 8];
#pragma unroll
        for (int j = 0; j < 4; j++)
            b[j] = *(const short8*)&Bs[(64 * wc + 16 * j + lr) * 32 + lg * 8];
#pragma unroll
        for (int i = 0; i < 4; i++)
#pragma unroll
            for (int j = 0; j < 4; j++)
                acc[i][j] = __builtin_amdgcn_mfma_f32_16x16x32_bf16(a[i], b[j], acc[i][j], 0, 0, 0);
    }

    if (MODE == 0) {
        // rows = tokens, cols = h*64+d. RoPE pairs (d, d+32) = (acc[i][j], acc[i][j+2]), j<2.
        u16* Op16 = (u16*)Op;
#pragma unroll
        for (int i = 0; i < 4; i++)
#pragma unroll
            for (int jj = 0; jj < 4; jj++) {
                long gr = brow + 64 * wr + 16 * i + lg * 4 + jj;
                long b_ = gr >> 11, t_ = gr & 2047;
#pragma unroll
                for (int j = 0; j < 2; j++) {
                    int di = 16 * j + lr; // 0..31
                    float c = CS[(t_ << 5) + di], s = SN[(t_ << 5) + di];
                    float x1 = acc[i][j][jj], x2 = acc[i][j + 2][jj];
                    float o1 = (x1 * c - x2 * s) * scl;
                    float o2 = (x2 * c + x1 * s) * scl;
                    long gc = bcol + 64 * wc + 16 * j + lr;
                    long h_ = gc >> 6;
                    long base = (((b_ * Hn + h_) * Tn + t_) << 6) + (gc & 63);
                    Op16[base] = f2bf(o1);
                    Op16[base + 32] = f2bf(o2);
                }
            }
    } else {
#pragma unroll
        for (int i = 0; i < 4; i++)
#pragma unroll
            for (int j = 0; j < 4; j++)
#pragma unroll
                for (int jj = 0; jj < 4; jj++) {
                    long gr = brow + 64 * wr + 16 * i + lg * 4 + jj;
                    long gc = bcol + 64 * wc + 16 * j + lr;
                    float v = acc[i][j][jj];
                    if (MODE == 1) {
                        ((float*)Op)[gr * N + gc] = v;
                    } else { // MODE 2: gr = c_out, gc = token
                        long h_ = gr >> 6, d_ = gr & 63, b_ = gc >> 11, t_ = gc & 2047;
                        ((u16*)Op)[((b_ * Hn + h_) * VROWS + d_) * TP + t_] = f2bf(v);
                    }
                }
    }
}

// ---------------- flash attention, causal, D=64 ----------------
// Q pre-scaled by QSCL (softmax in exp2 domain). VT has an l-column at row 64.
// 512-thread blocks (8 waves), one 32-row q-tile per wave. SIMD s hosts waves
// s and s+4 with qt = slot*4+s and 63-(slot*4+s): 33 KV-iters per SIMD-pair
// (balanced). 2 blocks/CU -> 16 waves/CU. XCD-swizzled: L2 caches 8 heads/XCD.
__global__ __launch_bounds__(512, 4) void attn_kernel(
    const u16* __restrict__ Q, const u16* __restrict__ K, const u16* __restrict__ VT,
    u16* __restrict__ Yb) {
    __shared__ u16 plds[8][32][68];

    int tid = threadIdx.x;
    int w = tid >> 6, lane = tid & 63;
    int lr = lane & 15, lg = lane >> 4;
    int gid = blockIdx.x;            // 0..511
    int xcd = gid & 7;
    int sl = gid >> 3;               // 0..63
    int bh = ((sl >> 3) << 3) + xcd; // 0..63
    int slot = sl & 7;               // 0..7
    int qt = (w < 4) ? slot * 4 + w : 63 - (slot * 4 + (w - 4));
    int q0 = qt * 32;

    const u16* Qp = Q + (long)bh * Tn * Dn;
    const u16* Kp = K + (long)bh * Tn * Dn;
    const u16* VTp = VT + (long)bh * VROWS * TP;
    long b_ = bh >> 4, h_ = bh & 15;

    short8 aq[2][2];
#pragma unroll
    for (int qi = 0; qi < 2; qi++)
#pragma unroll
        for (int ks = 0; ks < 2; ks++)
            aq[qi][ks] = *(const short8*)&Qp[(long)(q0 + qi * 16 + lr) * 64 + ks * 32 + lg * 8];

    f32x4 acc[2][5] = {};        // [qi][dblk]; dblk 4 = l-column
    float m_[2][4];
#pragma unroll
    for (int qi = 0; qi < 2; qi++)
#pragma unroll
        for (int jj = 0; jj < 4; jj++) m_[qi][jj] = -1e30f;

    auto iter = [&](auto mc, int kv0) {
        constexpr bool MASKED = decltype(mc)::value;
        // ---- issue all 18 global loads up front ----
        short8 bk[4][2];
#pragma unroll
        for (int cblk = 0; cblk < 4; cblk++) {
            const u16* kb = &Kp[(long)(kv0 + cblk * 16 + lr) * 64 + lg * 8];
            bk[cblk][0] = *(const short8*)kb;
            bk[cblk][1] = *(const short8*)(kb + 32);
        }
        short8 bv[2][5];
#pragma unroll
        for (int ks = 0; ks < 2; ks++)
#pragma unroll
            for (int dblk = 0; dblk < 5; dblk++)
                bv[ks][dblk] = *(const short8*)&VTp[(long)(dblk * 16 + lr) * TP + kv0 + ks * 32 + lg * 8];
        // ---- QK^T (scale pre-folded into Q) ----
        f32x4 s[2][4];
#pragma unroll
        for (int cblk = 0; cblk < 4; cblk++)
#pragma unroll
            for (int qi = 0; qi < 2; qi++) {
                f32x4 sc = {};
                sc = __builtin_amdgcn_mfma_f32_16x16x32_bf16(aq[qi][0], bk[cblk][0], sc, 0, 0, 0);
                sc = __builtin_amdgcn_mfma_f32_16x16x32_bf16(aq[qi][1], bk[cblk][1], sc, 0, 0, 0);
                if (MASKED) {
                    int col = kv0 + cblk * 16 + lr;
#pragma unroll
                    for (int jj = 0; jj < 4; jj++) {
                        int row = q0 + qi * 16 + lg * 4 + jj;
                        if (col > row) sc[jj] = -1e30f;
                    }
                }
                s[qi][cblk] = sc;
            }
        // ---- defer-max grow check (no cross-lane in common path) ----
        float pm[2][4];
        bool grow = false;
#pragma unroll
        for (int qi = 0; qi < 2; qi++)
#pragma unroll
            for (int jj = 0; jj < 4; jj++) {
                pm[qi][jj] = fmaxf(fmaxf(s[qi][0][jj], s[qi][1][jj]),
                                   fmaxf(s[qi][2][jj], s[qi][3][jj]));
                grow = grow || (pm[qi][jj] > m_[qi][jj] + 8.0f);
            }
        if (__any(grow)) {
#pragma unroll
            for (int qi = 0; qi < 2; qi++)
#pragma unroll
                for (int jj = 0; jj < 4; jj++) {
                    float v = pm[qi][jj];
                    v = fmaxf(v, __shfl_xor(v, 1));
                    v = fmaxf(v, __shfl_xor(v, 2));
                    v = fmaxf(v, __shfl_xor(v, 4));
                    v = fmaxf(v, __shfl_xor(v, 8));
                    float mn = fmaxf(m_[qi][jj], v);
                    float alpha = __builtin_amdgcn_exp2f(m_[qi][jj] - mn);
                    m_[qi][jj] = mn;
#pragma unroll
                    for (int dblk = 0; dblk < 5; dblk++) acc[qi][dblk][jj] *= alpha;
                }
        }
        // ---- P = exp2(s - m) -> LDS (C-layout -> A-frag fixup) ----
#pragma unroll
        for (int qi = 0; qi < 2; qi++)
#pragma unroll
            for (int cblk = 0; cblk < 4; cblk++)
#pragma unroll
                for (int jj = 0; jj < 4; jj++)
                    plds[w][qi * 16 + lg * 4 + jj][cblk * 16 + lr] =
                        f2bf(__builtin_amdgcn_exp2f(s[qi][cblk][jj] - m_[qi][jj]));
        short8 pa[2][2];
#pragma unroll
        for (int qi = 0; qi < 2; qi++)
#pragma unroll
            for (int ks = 0; ks < 2; ks++)
                pa[qi][ks] = *(const short8*)&plds[w][qi * 16 + lr][ks * 32 + lg * 8];
        // ---- PV (+l via ones-column, dblk=4) ----
#pragma unroll
        for (int ks = 0; ks < 2; ks++)
#pragma unroll
            for (int dblk = 0; dblk < 5; dblk++)
#pragma unroll
                for (int qi = 0; qi < 2; qi++)
                    acc[qi][dblk] = __builtin_amdgcn_mfma_f32_16x16x32_bf16(
                        pa[qi][ks], bv[ks][dblk], acc[qi][dblk], 0, 0, 0);
    };

    int kv_end = q0 + 32;
    int last = ((kv_end - 1) >> 6) << 6;  // exactly one masked tail block
    for (int kv0 = 0; kv0 < last; kv0 += 64)
        iter(std::integral_constant<bool, false>{}, kv0);
    iter(std::integral_constant<bool, true>{}, last);

    // ---- epilogue: broadcast l from lr==0 lanes, y = acc/l ----
#pragma unroll
    for (int qi = 0; qi < 2; qi++)
#pragma unroll
        for (int jj = 0; jj < 4; jj++) {
            float l = __shfl(acc[qi][4][jj], lane & 48);
            float rl = 1.0f / l;
            int row = q0 + qi * 16 + lg * 4 + jj;
#pragma unroll
            for (int dblk = 0; dblk < 4; dblk++) {
                int d = dblk * 16 + lr;
                Yb[((b_ * Tn + row) * Cn) + h_ * 64 + d] = f2bf(acc[qi][dblk][jj] * rl);
            }
        }
}

extern "C" void kernel_launch(void* const* d_in, const int* in_sizes, int n_in,
                              void* d_out, int out_size, void* d_ws, size_t ws_size,
                              hipStream_t stream) {
    const float* x  = (const float*)d_in[0];
    const float* wq = (const float*)d_in[1];
    const float* wk = (const float*)d_in[2];
    const float* wv = (const float*)d_in[3];
    const float* wp = (const float*)d_in[4];

    char* ws = (char*)d_ws;
    size_t off = 0;
    auto alloc = [&](size_t bytes) {
        char* p = ws + off;
        off += (bytes + 255) & ~(size_t)255;
        return p;
    };
    const size_t BTC = (size_t)Bsz * Tn * Cn;
    u16* xb  = (u16*)alloc(BTC * 2);
    u16* wqb = (u16*)alloc((size_t)Cn * Cn * 2);
    u16* wkb = (u16*)alloc((size_t)Cn * Cn * 2);
    u16* wvb = (u16*)alloc((size_t)Cn * Cn * 2);
    u16* wpb = (u16*)alloc((size_t)Cn * Cn * 2);
    u16* qr  = (u16*)alloc(BTC * 2);
    u16* kr  = (u16*)alloc(BTC * 2);
    u16* vt  = (u16*)alloc((size_t)64 * VROWS * TP * 2); // 21.3 MB
    float* cs = (float*)alloc((size_t)Tn * 32 * 4);
    float* sn = (float*)alloc((size_t)Tn * 32 * 4);
    u16* yb  = xb; // alias: xb dead after the V^T GEMM; attn writes yb afterwards

    int M = Bsz * Tn; // 8192
    cvt_kernel<<<1024, 256, 0, stream>>>(x, xb, (int)(BTC / 4));
    cvtw_kernel<<<dim3(Cn * Cn / 4 / 256, 4), 256, 0, stream>>>(
        wq, wk, wv, wp, wqb, wkb, wvb, wpb);
    trig_kernel<<<(Tn * 32) / 256, 256, 0, stream>>>(cs, sn);

    // Q,K projections with fused RoPE (+QSCL on Q) -> [B,H,T,D] bf16
    gemm_bt<0><<<dim3(M / 128, Cn / 128, 2), 256, 0, stream>>>(
        xb, wqb, wkb, qr, kr, cs, sn, M, Cn, Cn);

    // V^T = wv * x^T -> vt[bh][d][t] (TP stride), plus l-column fill
    gemm_bt<2><<<dim3(Cn / 128, M / 128), 256, 0, stream>>>(
        wvb, xb, nullptr, vt, nullptr, nullptr, nullptr, Cn, M, Cn);
    fill_ones<<<(64 * 16 * TP) / 256, 256, 0, stream>>>(vt);

    attn_kernel<<<dim3(512), 512, 0, stream>>>(qr, kr, vt, yb);

    // output projection -> fp32 d_out
    gemm_bt<1><<<dim3(M / 128, Cn / 128), 256, 0, stream>>>(
        yb, wpb, nullptr, d_out, nullptr, nullptr, nullptr, M, Cn, Cn);
}

// Round 6
// 265.285 us; speedup vs baseline: 1.3780x; 1.3780x over previous
//
#include <hip/hip_runtime.h>
#include <hip/hip_bf16.h>

typedef __attribute__((ext_vector_type(8))) short short8;
typedef __attribute__((ext_vector_type(4))) float f32x4;
typedef unsigned short u16;

#define DEV static __device__ __forceinline__

constexpr int Bsz = 4, Tn = 2048, Cn = 1024, Hn = 16, Dn = 64;
constexpr int TP = Tn + 32;  // padded VT row stride: 4160B, breaks 4KB channel aliasing
constexpr int VROWS = 80;    // 64 d-rows + row64=ones (l-column) + 15 zero rows
// QK^T scale folded into Q in the GEMM epilogue: 0.125 * log2(e); softmax in exp2 domain.
#define QSCL 0.1803368801111204f

DEV u16 f2bf(float f) {  // round-to-nearest (ties away): 2 VALU
    union { float f; unsigned u; } v{f};
    return (u16)((v.u + 0x8000u) >> 16);
}
DEV float bf2f(u16 u) {
    union { unsigned u; float f; } v;
    v.u = ((unsigned)u) << 16;
    return v.f;
}

DEV void gload_lds16(const void* g, void* l) {
    __builtin_amdgcn_global_load_lds((const __attribute__((address_space(1))) void*)g,
                                     (__attribute__((address_space(3))) void*)l, 16, 0, 0);
}

// ---------------- fp32 -> bf16 convert (vectorized) ----------------
__global__ void cvt_kernel(const float* __restrict__ in, u16* __restrict__ out, int n4) {
    int i = blockIdx.x * blockDim.x + threadIdx.x;
    int stride = gridDim.x * blockDim.x;
    for (; i < n4; i += stride) {
        float4 v = ((const float4*)in)[i];
        short4 o;
        o.x = (short)f2bf(v.x); o.y = (short)f2bf(v.y);
        o.z = (short)f2bf(v.z); o.w = (short)f2bf(v.w);
        ((short4*)out)[i] = o;
    }
}

// ---------------- 4 weight matrices in one launch ----------------
__global__ void cvtw_kernel(const float* __restrict__ w0, const float* __restrict__ w1,
                            const float* __restrict__ w2, const float* __restrict__ w3,
                            u16* o0, u16* o1, u16* o2, u16* o3) {
    const float* src = blockIdx.y == 0 ? w0 : blockIdx.y == 1 ? w1 : blockIdx.y == 2 ? w2 : w3;
    u16* dst = blockIdx.y == 0 ? o0 : blockIdx.y == 1 ? o1 : blockIdx.y == 2 ? o2 : o3;
    int i = blockIdx.x * blockDim.x + threadIdx.x;
    float4 v = ((const float4*)src)[i];
    short4 o;
    o.x = (short)f2bf(v.x); o.y = (short)f2bf(v.y);
    o.z = (short)f2bf(v.z); o.w = (short)f2bf(v.w);
    ((short4*)dst)[i] = o;
}

// ---------------- RoPE trig tables [T][32] ----------------
__global__ void trig_kernel(float* __restrict__ cs, float* __restrict__ sn) {
    int idx = blockIdx.x * blockDim.x + threadIdx.x; // Tn*32
    int t = idx >> 5, i = idx & 31;
    double inv = pow(10000.0, -(double)i / 32.0);
    double a = (double)t * inv;
    cs[idx] = (float)cos(a);
    sn[idx] = (float)sin(a);
}

// rows 64..79 of each VT head: row 64 = 1.0 (l-column), rows 65..79 = 0
__global__ void fill_ones(u16* __restrict__ vt) {
    long idx = (long)blockIdx.x * 256 + threadIdx.x; // 64*16*TP total
    long bh = idx / (16 * TP);
    long rem = idx % (16 * TP);
    long r = rem / TP, t = rem % TP;
    vt[(bh * VROWS + 64 + r) * TP + t] = (r == 0) ? (u16)0x3f80 : (u16)0;
}

// ---------------- 128x128 bf16 GEMM, C = A * B^T ----------------
// MODE 0: QK projections. grid.z in {0,1} selects (B0->O0)=Q / (B1->O1)=K.
//         Epilogue applies RoPE (thread-local: d and d+32 are acc[i][j], acc[i][j+2])
//         and QSCL for Q; writes bf16 [B,H,T,D].
// MODE 1: fp32 row-major [M,N] (output projection).
// MODE 2: V^T producer: A=wv, B=x -> C[c_out][bt]; writes bf16 vt[bh][d][t] (TP stride).
template <int MODE>
__global__ __launch_bounds__(256, 2) void gemm_bt(
    const u16* __restrict__ A,
    const u16* __restrict__ B0, const u16* __restrict__ B1,
    void* __restrict__ O0, void* __restrict__ O1,
    const float* __restrict__ CS, const float* __restrict__ SN,
    int M, int N, int K) {
    __shared__ u16 As[128 * 32];
    __shared__ u16 Bs[128 * 32];

    const u16* Bp = B0;
    void* Op = O0;
    float scl = 1.0f;
    if (MODE == 0) {
        if (blockIdx.z == 1) { Bp = B1; Op = O1; }
        else scl = QSCL;
    }
    int tid = threadIdx.x;
    int w = tid >> 6, lane = tid & 63;
    int lr = lane & 15, lg = lane >> 4;
    int wr = w >> 1, wc = w & 1;
    long brow = (long)blockIdx.x * 128, bcol = (long)blockIdx.y * 128;

    f32x4 acc[4][4] = {};
    const u16* Arow = A + brow * K;
    const u16* Brow = Bp + bcol * K;

    for (int k0 = 0; k0 < K; k0 += 32) {
        __syncthreads();
#pragma unroll
        for (int c = 0; c < 2; c++) {
            int idx = c * 256 + tid;
            int row = idx >> 2, col = (idx & 3) << 3;
            const u16* ga = Arow + (long)row * K + k0 + col;
            const u16* gb = Brow + (long)row * K + k0 + col;
            char* la = (char*)As + (size_t)(c * 256 + (tid & 192)) * 16;
            char* lb = (char*)Bs + (size_t)(c * 256 + (tid & 192)) * 16;
            gload_lds16(ga, la);
            gload_lds16(gb, lb);
        }
        __syncthreads();
        short8 a[4], b[4];
#pragma unroll
        for (int i = 0; i < 4; i++)
            a[i] = *(const short8*)&As[(64 * wr + 16 * i + lr) * 32 + lg * 8];
#pragma unroll
        for (int j = 0; j < 4; j++)
            b[j] = *(const short8*)&Bs[(64 * wc + 16 * j + lr) * 32 + lg * 8];
#pragma unroll
        for (int i = 0; i < 4; i++)
#pragma unroll
            for (int j = 0; j < 4; j++)
                acc[i][j] = __builtin_amdgcn_mfma_f32_16x16x32_bf16(a[i], b[j], acc[i][j], 0, 0, 0);
    }

    if (MODE == 0) {
        // rows = tokens, cols = h*64+d. RoPE pairs (d, d+32) = (acc[i][j], acc[i][j+2]), j<2.
        u16* Op16 = (u16*)Op;
#pragma unroll
        for (int i = 0; i < 4; i++)
#pragma unroll
            for (int jj = 0; jj < 4; jj++) {
                long gr = brow + 64 * wr + 16 * i + lg * 4 + jj;
                long b_ = gr >> 11, t_ = gr & 2047;
#pragma unroll
                for (int j = 0; j < 2; j++) {
                    int di = 16 * j + lr; // 0..31
                    float c = CS[(t_ << 5) + di], s = SN[(t_ << 5) + di];
                    float x1 = acc[i][j][jj], x2 = acc[i][j + 2][jj];
                    float o1 = (x1 * c - x2 * s) * scl;
                    float o2 = (x2 * c + x1 * s) * scl;
                    long gc = bcol + 64 * wc + 16 * j + lr;
                    long h_ = gc >> 6;
                    long base = (((b_ * Hn + h_) * Tn + t_) << 6) + (gc & 63);
                    Op16[base] = f2bf(o1);
                    Op16[base + 32] = f2bf(o2);
                }
            }
    } else {
#pragma unroll
        for (int i = 0; i < 4; i++)
#pragma unroll
            for (int j = 0; j < 4; j++)
#pragma unroll
                for (int jj = 0; jj < 4; jj++) {
                    long gr = brow + 64 * wr + 16 * i + lg * 4 + jj;
                    long gc = bcol + 64 * wc + 16 * j + lr;
                    float v = acc[i][j][jj];
                    if (MODE == 1) {
                        ((float*)Op)[gr * N + gc] = v;
                    } else { // MODE 2: gr = c_out, gc = token
                        long h_ = gr >> 6, d_ = gr & 63, b_ = gc >> 11, t_ = gc & 2047;
                        ((u16*)Op)[((b_ * Hn + h_) * VROWS + d_) * TP + t_] = f2bf(v);
                    }
                }
    }
}

// ---------------- flash attention, causal, D=64, split-KV ----------------
// Q pre-scaled by QSCL (softmax in exp2 domain). VT has an l-column at row 64.
// Grid 1024 x 256 threads. Each block: 2 wave-groups; group g owns q-tile pair
// (p, 63-p), p = slot*2+g. Sibling waves (h=0/1) each run HALF of every tile's
// KV range (~16.5 iters/wave, balanced), then merge (m, acc) via LDS.
// launch_bounds(256,3): reg cap ~170 > ~140 live set -> no spill (round-5 lesson),
// 3 waves/SIMD by registers.
__global__ __launch_bounds__(256, 3) void attn_kernel(
    const u16* __restrict__ Q, const u16* __restrict__ K, const u16* __restrict__ VT,
    u16* __restrict__ Yb) {
    __shared__ u16 plds[4][32][68];
    __shared__ float mrg[2][64][48];  // [group][lane][40 acc + 8 m]

    int tid = threadIdx.x;
    int w = tid >> 6, lane = tid & 63;
    int lr = lane & 15, lg = lane >> 4;
    int gid = blockIdx.x;            // 0..1023
    int xcd = gid & 7;
    int sl = gid >> 3;               // 0..127
    int bh = ((sl >> 4) << 3) + xcd; // 0..63
    int slot = sl & 15;              // 0..15
    int p = slot * 2 + (w >> 1);     // pair index 0..31
    int h = w & 1;                   // KV-half owner
    int grp = w >> 1;

    const u16* Qp = Q + (long)bh * Tn * Dn;
    const u16* Kp = K + (long)bh * Tn * Dn;
    const u16* VTp = VT + (long)bh * VROWS * TP;
    long b_ = bh >> 4, h_ = bh & 15;

#pragma unroll
    for (int pass = 0; pass < 2; pass++) {
        int qt = pass == 0 ? p : 63 - p;
        int q0 = qt * 32;

        short8 aq[2][2];
#pragma unroll
        for (int qi = 0; qi < 2; qi++)
#pragma unroll
            for (int ks = 0; ks < 2; ks++)
                aq[qi][ks] = *(const short8*)&Qp[(long)(q0 + qi * 16 + lr) * 64 + ks * 32 + lg * 8];

        f32x4 acc[2][5] = {};        // [qi][dblk]; dblk 4 = l-column
        float m_[2][4];
#pragma unroll
        for (int qi = 0; qi < 2; qi++)
#pragma unroll
            for (int jj = 0; jj < 4; jj++) m_[qi][jj] = -1e30f;

        auto iter = [&](auto mc, int kv0) {
            constexpr bool MASKED = decltype(mc)::value;
            // ---- issue all 18 global loads up front ----
            short8 bk[4][2];
#pragma unroll
            for (int cblk = 0; cblk < 4; cblk++) {
                const u16* kb = &Kp[(long)(kv0 + cblk * 16 + lr) * 64 + lg * 8];
                bk[cblk][0] = *(const short8*)kb;
                bk[cblk][1] = *(const short8*)(kb + 32);
            }
            short8 bv[2][5];
#pragma unroll
            for (int ks = 0; ks < 2; ks++)
#pragma unroll
                for (int dblk = 0; dblk < 5; dblk++)
                    bv[ks][dblk] = *(const short8*)&VTp[(long)(dblk * 16 + lr) * TP + kv0 + ks * 32 + lg * 8];
            // ---- QK^T (scale pre-folded into Q) ----
            f32x4 s[2][4];
#pragma unroll
            for (int cblk = 0; cblk < 4; cblk++)
#pragma unroll
                for (int qi = 0; qi < 2; qi++) {
                    f32x4 sc = {};
                    sc = __builtin_amdgcn_mfma_f32_16x16x32_bf16(aq[qi][0], bk[cblk][0], sc, 0, 0, 0);
                    sc = __builtin_amdgcn_mfma_f32_16x16x32_bf16(aq[qi][1], bk[cblk][1], sc, 0, 0, 0);
                    if (MASKED) {
                        int col = kv0 + cblk * 16 + lr;
#pragma unroll
                        for (int jj = 0; jj < 4; jj++) {
                            int row = q0 + qi * 16 + lg * 4 + jj;
                            if (col > row) sc[jj] = -1e30f;
                        }
                    }
                    s[qi][cblk] = sc;
                }
            // ---- defer-max grow check (no cross-lane in common path) ----
            float pm[2][4];
            bool grow = false;
#pragma unroll
            for (int qi = 0; qi < 2; qi++)
#pragma unroll
                for (int jj = 0; jj < 4; jj++) {
                    pm[qi][jj] = fmaxf(fmaxf(s[qi][0][jj], s[qi][1][jj]),
                                       fmaxf(s[qi][2][jj], s[qi][3][jj]));
                    grow = grow || (pm[qi][jj] > m_[qi][jj] + 8.0f);
                }
            if (__any(grow)) {
#pragma unroll
                for (int qi = 0; qi < 2; qi++)
#pragma unroll
                    for (int jj = 0; jj < 4; jj++) {
                        float v = pm[qi][jj];
                        v = fmaxf(v, __shfl_xor(v, 1));
                        v = fmaxf(v, __shfl_xor(v, 2));
                        v = fmaxf(v, __shfl_xor(v, 4));
                        v = fmaxf(v, __shfl_xor(v, 8));
                        float mn = fmaxf(m_[qi][jj], v);
                        float alpha = __builtin_amdgcn_exp2f(m_[qi][jj] - mn);
                        m_[qi][jj] = mn;
#pragma unroll
                        for (int dblk = 0; dblk < 5; dblk++) acc[qi][dblk][jj] *= alpha;
                    }
            }
            // ---- P = exp2(s - m) -> LDS (C-layout -> A-frag fixup) ----
#pragma unroll
            for (int qi = 0; qi < 2; qi++)
#pragma unroll
                for (int cblk = 0; cblk < 4; cblk++)
#pragma unroll
                    for (int jj = 0; jj < 4; jj++)
                        plds[w][qi * 16 + lg * 4 + jj][cblk * 16 + lr] =
                            f2bf(__builtin_amdgcn_exp2f(s[qi][cblk][jj] - m_[qi][jj]));
            short8 pa[2][2];
#pragma unroll
            for (int qi = 0; qi < 2; qi++)
#pragma unroll
                for (int ks = 0; ks < 2; ks++)
                    pa[qi][ks] = *(const short8*)&plds[w][qi * 16 + lr][ks * 32 + lg * 8];
            // ---- PV (+l via ones-column, dblk=4) ----
#pragma unroll
            for (int ks = 0; ks < 2; ks++)
#pragma unroll
                for (int dblk = 0; dblk < 5; dblk++)
#pragma unroll
                    for (int qi = 0; qi < 2; qi++)
                        acc[qi][dblk] = __builtin_amdgcn_mfma_f32_16x16x32_bf16(
                            pa[qi][ks], bv[ks][dblk], acc[qi][dblk], 0, 0, 0);
        };

        int n = (qt + 2) >> 1;  // # of 64-wide KV blocks = ceil((qt+1)/2)
        int nA = n >> 1;        // first-half size (h=0); h=1 gets [nA, n) incl masked tail
        if (h == 0) {
            for (int ib = 0; ib < nA; ib++)
                iter(std::integral_constant<bool, false>{}, ib * 64);
        } else {
            for (int ib = nA; ib < n - 1; ib++)
                iter(std::integral_constant<bool, false>{}, ib * 64);
            iter(std::integral_constant<bool, true>{}, (n - 1) * 64);
        }

        // ---- sibling merge: h=1 publishes (acc, m), h=0 merges + writes ----
        if (h == 1) {
#pragma unroll
            for (int qi = 0; qi < 2; qi++) {
#pragma unroll
                for (int dblk = 0; dblk < 5; dblk++)
#pragma unroll
                    for (int jj = 0; jj < 4; jj++)
                        mrg[grp][lane][(qi * 5 + dblk) * 4 + jj] = acc[qi][dblk][jj];
#pragma unroll
                for (int jj = 0; jj < 4; jj++)
                    mrg[grp][lane][40 + qi * 4 + jj] = m_[qi][jj];
            }
        }
        __syncthreads();
        if (h == 0) {
#pragma unroll
            for (int qi = 0; qi < 2; qi++)
#pragma unroll
                for (int jj = 0; jj < 4; jj++) {
                    float mB = mrg[grp][lane][40 + qi * 4 + jj];
                    float M = fmaxf(m_[qi][jj], mB);
                    float aA = __builtin_amdgcn_exp2f(m_[qi][jj] - M);
                    float aB = __builtin_amdgcn_exp2f(mB - M);
#pragma unroll
                    for (int dblk = 0; dblk < 5; dblk++)
                        acc[qi][dblk][jj] = acc[qi][dblk][jj] * aA +
                                            mrg[grp][lane][(qi * 5 + dblk) * 4 + jj] * aB;
                }
            // epilogue: broadcast l from lr==0 lanes, y = acc/l
#pragma unroll
            for (int qi = 0; qi < 2; qi++)
#pragma unroll
                for (int jj = 0; jj < 4; jj++) {
                    float l = __shfl(acc[qi][4][jj], lane & 48);
                    float rl = 1.0f / l;
                    int row = q0 + qi * 16 + lg * 4 + jj;
#pragma unroll
                    for (int dblk = 0; dblk < 4; dblk++) {
                        int d = dblk * 16 + lr;
                        Yb[((b_ * Tn + row) * Cn) + h_ * 64 + d] = f2bf(acc[qi][dblk][jj] * rl);
                    }
                }
        }
        __syncthreads();  // mrg reused next pass
    }
}

extern "C" void kernel_launch(void* const* d_in, const int* in_sizes, int n_in,
                              void* d_out, int out_size, void* d_ws, size_t ws_size,
                              hipStream_t stream) {
    const float* x  = (const float*)d_in[0];
    const float* wq = (const float*)d_in[1];
    const float* wk = (const float*)d_in[2];
    const float* wv = (const float*)d_in[3];
    const float* wp = (const float*)d_in[4];

    char* ws = (char*)d_ws;
    size_t off = 0;
    auto alloc = [&](size_t bytes) {
        char* p = ws + off;
        off += (bytes + 255) & ~(size_t)255;
        return p;
    };
    const size_t BTC = (size_t)Bsz * Tn * Cn;
    u16* xb  = (u16*)alloc(BTC * 2);
    u16* wqb = (u16*)alloc((size_t)Cn * Cn * 2);
    u16* wkb = (u16*)alloc((size_t)Cn * Cn * 2);
    u16* wvb = (u16*)alloc((size_t)Cn * Cn * 2);
    u16* wpb = (u16*)alloc((size_t)Cn * Cn * 2);
    u16* qr  = (u16*)alloc(BTC * 2);
    u16* kr  = (u16*)alloc(BTC * 2);
    u16* vt  = (u16*)alloc((size_t)64 * VROWS * TP * 2); // 21.3 MB
    float* cs = (float*)alloc((size_t)Tn * 32 * 4);
    float* sn = (float*)alloc((size_t)Tn * 32 * 4);
    u16* yb  = xb; // alias: xb dead after the V^T GEMM; attn writes yb afterwards

    int M = Bsz * Tn; // 8192
    cvt_kernel<<<1024, 256, 0, stream>>>(x, xb, (int)(BTC / 4));
    cvtw_kernel<<<dim3(Cn * Cn / 4 / 256, 4), 256, 0, stream>>>(
        wq, wk, wv, wp, wqb, wkb, wvb, wpb);
    trig_kernel<<<(Tn * 32) / 256, 256, 0, stream>>>(cs, sn);

    // Q,K projections with fused RoPE (+QSCL on Q) -> [B,H,T,D] bf16
    gemm_bt<0><<<dim3(M / 128, Cn / 128, 2), 256, 0, stream>>>(
        xb, wqb, wkb, qr, kr, cs, sn, M, Cn, Cn);

    // V^T = wv * x^T -> vt[bh][d][t] (TP stride), plus l-column fill
    gemm_bt<2><<<dim3(Cn / 128, M / 128), 256, 0, stream>>>(
        wvb, xb, nullptr, vt, nullptr, nullptr, nullptr, Cn, M, Cn);
    fill_ones<<<(64 * 16 * TP) / 256, 256, 0, stream>>>(vt);

    attn_kernel<<<dim3(1024), 256, 0, stream>>>(qr, kr, vt, yb);

    // output projection -> fp32 d_out
    gemm_bt<1><<<dim3(M / 128, Cn / 128), 256, 0, stream>>>(
        yb, wpb, nullptr, d_out, nullptr, nullptr, nullptr, M, Cn, Cn);
}

// Round 7
// 209.104 us; speedup vs baseline: 1.7483x; 1.2687x over previous
//
#include <hip/hip_runtime.h>
#include <hip/hip_bf16.h>

typedef __attribute__((ext_vector_type(8))) short short8;
typedef __attribute__((ext_vector_type(4))) float f32x4;
typedef unsigned short u16;

#define DEV static __device__ __forceinline__

constexpr int Bsz = 4, Tn = 2048, Cn = 1024, Hn = 16, Dn = 64;
constexpr int TP = Tn + 32;  // padded VT row stride: 4160B, breaks 4KB channel aliasing
constexpr int VROWS = 64;    // d-rows only; l-column B-frag synthesized in registers
// QK^T scale folded into Q in the GEMM epilogue: 0.125 * log2(e); softmax in exp2 domain.
#define QSCL 0.1803368801111204f

DEV u16 f2bf(float f) {  // round-to-nearest (ties away): 2 VALU
    union { float f; unsigned u; } v{f};
    return (u16)((v.u + 0x8000u) >> 16);
}
DEV float bf2f(u16 u) {
    union { unsigned u; float f; } v;
    v.u = ((unsigned)u) << 16;
    return v.f;
}

DEV void gload_lds16(const void* g, void* l) {
    __builtin_amdgcn_global_load_lds((const __attribute__((address_space(1))) void*)g,
                                     (__attribute__((address_space(3))) void*)l, 16, 0, 0);
}

// ---------------- fp32 -> bf16 convert (vectorized) ----------------
__global__ void cvt_kernel(const float* __restrict__ in, u16* __restrict__ out, int n4) {
    int i = blockIdx.x * blockDim.x + threadIdx.x;
    int stride = gridDim.x * blockDim.x;
    for (; i < n4; i += stride) {
        float4 v = ((const float4*)in)[i];
        short4 o;
        o.x = (short)f2bf(v.x); o.y = (short)f2bf(v.y);
        o.z = (short)f2bf(v.z); o.w = (short)f2bf(v.w);
        ((short4*)out)[i] = o;
    }
}

// ---------------- 4 weight matrices in one launch ----------------
__global__ void cvtw_kernel(const float* __restrict__ w0, const float* __restrict__ w1,
                            const float* __restrict__ w2, const float* __restrict__ w3,
                            u16* o0, u16* o1, u16* o2, u16* o3) {
    const float* src = blockIdx.y == 0 ? w0 : blockIdx.y == 1 ? w1 : blockIdx.y == 2 ? w2 : w3;
    u16* dst = blockIdx.y == 0 ? o0 : blockIdx.y == 1 ? o1 : blockIdx.y == 2 ? o2 : o3;
    int i = blockIdx.x * blockDim.x + threadIdx.x;
    float4 v = ((const float4*)src)[i];
    short4 o;
    o.x = (short)f2bf(v.x); o.y = (short)f2bf(v.y);
    o.z = (short)f2bf(v.z); o.w = (short)f2bf(v.w);
    ((short4*)dst)[i] = o;
}

// ---------------- RoPE trig tables [T][32] ----------------
__global__ void trig_kernel(float* __restrict__ cs, float* __restrict__ sn) {
    int idx = blockIdx.x * blockDim.x + threadIdx.x; // Tn*32
    int t = idx >> 5, i = idx & 31;
    double inv = pow(10000.0, -(double)i / 32.0);
    double a = (double)t * inv;
    cs[idx] = (float)cos(a);
    sn[idx] = (float)sin(a);
}

// ---------------- 128x128 bf16 GEMM, C = A * B^T ----------------
// MODE 0: QK projections. grid.z in {0,1} selects (B0->O0)=Q / (B1->O1)=K.
//         Epilogue applies RoPE (thread-local: d and d+32 are acc[i][j], acc[i][j+2])
//         and QSCL for Q; writes bf16 [B,H,T,D].
// MODE 1: fp32 row-major [M,N] (output projection).
// MODE 2: V^T producer: A=wv, B=x -> C[c_out][bt]; writes bf16 vt[bh][d][t] (TP stride).
template <int MODE>
__global__ __launch_bounds__(256, 2) void gemm_bt(
    const u16* __restrict__ A,
    const u16* __restrict__ B0, const u16* __restrict__ B1,
    void* __restrict__ O0, void* __restrict__ O1,
    const float* __restrict__ CS, const float* __restrict__ SN,
    int M, int N, int K) {
    __shared__ u16 As[128 * 32];
    __shared__ u16 Bs[128 * 32];

    const u16* Bp = B0;
    void* Op = O0;
    float scl = 1.0f;
    if (MODE == 0) {
        if (blockIdx.z == 1) { Bp = B1; Op = O1; }
        else scl = QSCL;
    }
    int tid = threadIdx.x;
    int w = tid >> 6, lane = tid & 63;
    int lr = lane & 15, lg = lane >> 4;
    int wr = w >> 1, wc = w & 1;
    long brow = (long)blockIdx.x * 128, bcol = (long)blockIdx.y * 128;

    f32x4 acc[4][4] = {};
    const u16* Arow = A + brow * K;
    const u16* Brow = Bp + bcol * K;

    for (int k0 = 0; k0 < K; k0 += 32) {
        __syncthreads();
#pragma unroll
        for (int c = 0; c < 2; c++) {
            int idx = c * 256 + tid;
            int row = idx >> 2, col = (idx & 3) << 3;
            const u16* ga = Arow + (long)row * K + k0 + col;
            const u16* gb = Brow + (long)row * K + k0 + col;
            char* la = (char*)As + (size_t)(c * 256 + (tid & 192)) * 16;
            char* lb = (char*)Bs + (size_t)(c * 256 + (tid & 192)) * 16;
            gload_lds16(ga, la);
            gload_lds16(gb, lb);
        }
        __syncthreads();
        short8 a[4], b[4];
#pragma unroll
        for (int i = 0; i < 4; i++)
            a[i] = *(const short8*)&As[(64 * wr + 16 * i + lr) * 32 + lg * 8];
#pragma unroll
        for (int j = 0; j < 4; j++)
            b[j] = *(const short8*)&Bs[(64 * wc + 16 * j + lr) * 32 + lg * 8];
#pragma unroll
        for (int i = 0; i < 4; i++)
#pragma unroll
            for (int j = 0; j < 4; j++)
                acc[i][j] = __builtin_amdgcn_mfma_f32_16x16x32_bf16(a[i], b[j], acc[i][j], 0, 0, 0);
    }

    if (MODE == 0) {
        // rows = tokens, cols = h*64+d. RoPE pairs (d, d+32) = (acc[i][j], acc[i][j+2]), j<2.
        u16* Op16 = (u16*)Op;
#pragma unroll
        for (int i = 0; i < 4; i++)
#pragma unroll
            for (int jj = 0; jj < 4; jj++) {
                long gr = brow + 64 * wr + 16 * i + lg * 4 + jj;
                long b_ = gr >> 11, t_ = gr & 2047;
#pragma unroll
                for (int j = 0; j < 2; j++) {
                    int di = 16 * j + lr; // 0..31
                    float c = CS[(t_ << 5) + di], s = SN[(t_ << 5) + di];
                    float x1 = acc[i][j][jj], x2 = acc[i][j + 2][jj];
                    float o1 = (x1 * c - x2 * s) * scl;
                    float o2 = (x2 * c + x1 * s) * scl;
                    long gc = bcol + 64 * wc + 16 * j + lr;
                    long h_ = gc >> 6;
                    long base = (((b_ * Hn + h_) * Tn + t_) << 6) + (gc & 63);
                    Op16[base] = f2bf(o1);
                    Op16[base + 32] = f2bf(o2);
                }
            }
    } else {
#pragma unroll
        for (int i = 0; i < 4; i++)
#pragma unroll
            for (int j = 0; j < 4; j++)
#pragma unroll
                for (int jj = 0; jj < 4; jj++) {
                    long gr = brow + 64 * wr + 16 * i + lg * 4 + jj;
                    long gc = bcol + 64 * wc + 16 * j + lr;
                    float v = acc[i][j][jj];
                    if (MODE == 1) {
                        ((float*)Op)[gr * N + gc] = v;
                    } else { // MODE 2: gr = c_out, gc = token
                        long h_ = gr >> 6, d_ = gr & 63, b_ = gc >> 11, t_ = gc & 2047;
                        ((u16*)Op)[((b_ * Hn + h_) * VROWS + d_) * TP + t_] = f2bf(v);
                    }
                }
    }
}

// ---------------- flash attention, causal, D=64 ----------------
// Round-4 structure (proven 115us) + K register prefetch + constant l-frag.
// Q pre-scaled by QSCL (softmax in exp2 domain). 256-thread blocks, 4 waves,
// folded q-tile pairs (p, 63-p): constant work/wave, no barriers. XCD-swizzled:
// each XCD's L2 caches 8 heads. bk(i+1) loaded during iter i -> QK^T never
// waits on K; bv issued at iter top, latency covered by QK^T+softmax.
__global__ __launch_bounds__(256, 2) void attn_kernel(
    const u16* __restrict__ Q, const u16* __restrict__ K, const u16* __restrict__ VT,
    u16* __restrict__ Yb) {
    __shared__ u16 plds[4][32][68];

    int tid = threadIdx.x;
    int w = tid >> 6, lane = tid & 63;
    int lr = lane & 15, lg = lane >> 4;
    int gid = blockIdx.x;            // 0..511
    int xcd = gid & 7;
    int sl = gid >> 3;               // 0..63
    int bh = ((sl >> 3) << 3) + xcd; // 0..63
    int pairi = (sl & 7) * 4 + w;    // 0..31

    const u16* Qp = Q + (long)bh * Tn * Dn;
    const u16* Kp = K + (long)bh * Tn * Dn;
    const u16* VTp = VT + (long)bh * VROWS * TP;
    long b_ = bh >> 4, h_ = bh & 15;

    // constant l-column B-frag: B[k][n] = (n==0) -> lanes with lr==0 hold 1.0bf
    short8 onesf;
#pragma unroll
    for (int j = 0; j < 8; j++) onesf[j] = (lr == 0) ? (short)0x3f80 : (short)0;

#pragma unroll
    for (int pass = 0; pass < 2; pass++) {
        int qt = pass == 0 ? pairi : 63 - pairi;
        int q0 = qt * 32;

        short8 aq[2][2];
#pragma unroll
        for (int qi = 0; qi < 2; qi++)
#pragma unroll
            for (int ks = 0; ks < 2; ks++)
                aq[qi][ks] = *(const short8*)&Qp[(long)(q0 + qi * 16 + lr) * 64 + ks * 32 + lg * 8];

        f32x4 acc[2][5] = {};        // [qi][dblk]; dblk 4 = l-column
        float m_[2][4];
#pragma unroll
        for (int qi = 0; qi < 2; qi++)
#pragma unroll
            for (int jj = 0; jj < 4; jj++) m_[qi][jj] = -1e30f;

        short8 bkc[4][2];            // current K tile (prefetched)
        auto load_bk = [&](short8 dst[4][2], int kv0) {
#pragma unroll
            for (int cblk = 0; cblk < 4; cblk++) {
                const u16* kb = &Kp[(long)(kv0 + cblk * 16 + lr) * 64 + lg * 8];
                dst[cblk][0] = *(const short8*)kb;
                dst[cblk][1] = *(const short8*)(kb + 32);
            }
        };
        load_bk(bkc, 0);

        auto iter = [&](auto mc, auto pfc, int kv0) {
            constexpr bool MASKED = decltype(mc)::value;
            constexpr bool PF = decltype(pfc)::value;
            // ---- issue V loads (consumed at PV, latency under QK^T+softmax) ----
            short8 bv[2][4];
#pragma unroll
            for (int ks = 0; ks < 2; ks++)
#pragma unroll
                for (int dblk = 0; dblk < 4; dblk++)
                    bv[ks][dblk] = *(const short8*)&VTp[(long)(dblk * 16 + lr) * TP + kv0 + ks * 32 + lg * 8];
            // ---- prefetch next K tile (consumed next iter / masked tail) ----
            short8 bkn[4][2];
            if (PF) load_bk(bkn, kv0 + 64);
            // ---- QK^T on resident bkc (no vm wait) ----
            f32x4 s[2][4];
#pragma unroll
            for (int cblk = 0; cblk < 4; cblk++)
#pragma unroll
                for (int qi = 0; qi < 2; qi++) {
                    f32x4 sc = {};
                    sc = __builtin_amdgcn_mfma_f32_16x16x32_bf16(aq[qi][0], bkc[cblk][0], sc, 0, 0, 0);
                    sc = __builtin_amdgcn_mfma_f32_16x16x32_bf16(aq[qi][1], bkc[cblk][1], sc, 0, 0, 0);
                    if (MASKED) {
                        int col = kv0 + cblk * 16 + lr;
#pragma unroll
                        for (int jj = 0; jj < 4; jj++) {
                            int row = q0 + qi * 16 + lg * 4 + jj;
                            if (col > row) sc[jj] = -1e30f;
                        }
                    }
                    s[qi][cblk] = sc;
                }
            // ---- defer-max grow check (no cross-lane in common path) ----
            float pm[2][4];
            bool grow = false;
#pragma unroll
            for (int qi = 0; qi < 2; qi++)
#pragma unroll
                for (int jj = 0; jj < 4; jj++) {
                    pm[qi][jj] = fmaxf(fmaxf(s[qi][0][jj], s[qi][1][jj]),
                                       fmaxf(s[qi][2][jj], s[qi][3][jj]));
                    grow = grow || (pm[qi][jj] > m_[qi][jj] + 8.0f);
                }
            if (__any(grow)) {
#pragma unroll
                for (int qi = 0; qi < 2; qi++)
#pragma unroll
                    for (int jj = 0; jj < 4; jj++) {
                        float v = pm[qi][jj];
                        v = fmaxf(v, __shfl_xor(v, 1));
                        v = fmaxf(v, __shfl_xor(v, 2));
                        v = fmaxf(v, __shfl_xor(v, 4));
                        v = fmaxf(v, __shfl_xor(v, 8));
                        float mn = fmaxf(m_[qi][jj], v);
                        float alpha = __builtin_amdgcn_exp2f(m_[qi][jj] - mn);
                        m_[qi][jj] = mn;
#pragma unroll
                        for (int dblk = 0; dblk < 5; dblk++) acc[qi][dblk][jj] *= alpha;
                    }
            }
            // ---- P = exp2(s - m) -> LDS (C-layout -> A-frag fixup) ----
#pragma unroll
            for (int qi = 0; qi < 2; qi++)
#pragma unroll
                for (int cblk = 0; cblk < 4; cblk++)
#pragma unroll
                    for (int jj = 0; jj < 4; jj++)
                        plds[w][qi * 16 + lg * 4 + jj][cblk * 16 + lr] =
                            f2bf(__builtin_amdgcn_exp2f(s[qi][cblk][jj] - m_[qi][jj]));
            short8 pa[2][2];
#pragma unroll
            for (int qi = 0; qi < 2; qi++)
#pragma unroll
                for (int ks = 0; ks < 2; ks++)
                    pa[qi][ks] = *(const short8*)&plds[w][qi * 16 + lr][ks * 32 + lg * 8];
            // ---- PV (+l via constant ones-frag) ----
#pragma unroll
            for (int ks = 0; ks < 2; ks++) {
#pragma unroll
                for (int dblk = 0; dblk < 4; dblk++)
#pragma unroll
                    for (int qi = 0; qi < 2; qi++)
                        acc[qi][dblk] = __builtin_amdgcn_mfma_f32_16x16x32_bf16(
                            pa[qi][ks], bv[ks][dblk], acc[qi][dblk], 0, 0, 0);
#pragma unroll
                for (int qi = 0; qi < 2; qi++)
                    acc[qi][4] = __builtin_amdgcn_mfma_f32_16x16x32_bf16(
                        pa[qi][ks], onesf, acc[qi][4], 0, 0, 0);
            }
            // ---- rotate prefetched K ----
            if (PF)
#pragma unroll
                for (int cblk = 0; cblk < 4; cblk++)
#pragma unroll
                    for (int ks = 0; ks < 2; ks++)
                        bkc[cblk][ks] = bkn[cblk][ks];
        };

        int kv_end = q0 + 32;
        int last = ((kv_end - 1) >> 6) << 6;  // exactly one masked tail block
        for (int kv0 = 0; kv0 < last; kv0 += 64)
            iter(std::integral_constant<bool, false>{}, std::integral_constant<bool, true>{}, kv0);
        iter(std::integral_constant<bool, true>{}, std::integral_constant<bool, false>{}, last);

        // ---- epilogue: broadcast l from lr==0 lanes, y = acc/l ----
#pragma unroll
        for (int qi = 0; qi < 2; qi++)
#pragma unroll
            for (int jj = 0; jj < 4; jj++) {
                float l = __shfl(acc[qi][4][jj], lane & 48);
                float rl = 1.0f / l;
                int row = q0 + qi * 16 + lg * 4 + jj;
#pragma unroll
                for (int dblk = 0; dblk < 4; dblk++) {
                    int d = dblk * 16 + lr;
                    Yb[((b_ * Tn + row) * Cn) + h_ * 64 + d] = f2bf(acc[qi][dblk][jj] * rl);
                }
            }
    }
}

extern "C" void kernel_launch(void* const* d_in, const int* in_sizes, int n_in,
                              void* d_out, int out_size, void* d_ws, size_t ws_size,
                              hipStream_t stream) {
    const float* x  = (const float*)d_in[0];
    const float* wq = (const float*)d_in[1];
    const float* wk = (const float*)d_in[2];
    const float* wv = (const float*)d_in[3];
    const float* wp = (const float*)d_in[4];

    char* ws = (char*)d_ws;
    size_t off = 0;
    auto alloc = [&](size_t bytes) {
        char* p = ws + off;
        off += (bytes + 255) & ~(size_t)255;
        return p;
    };
    const size_t BTC = (size_t)Bsz * Tn * Cn;
    u16* xb  = (u16*)alloc(BTC * 2);
    u16* wqb = (u16*)alloc((size_t)Cn * Cn * 2);
    u16* wkb = (u16*)alloc((size_t)Cn * Cn * 2);
    u16* wvb = (u16*)alloc((size_t)Cn * Cn * 2);
    u16* wpb = (u16*)alloc((size_t)Cn * Cn * 2);
    u16* qr  = (u16*)alloc(BTC * 2);
    u16* kr  = (u16*)alloc(BTC * 2);
    u16* vt  = (u16*)alloc((size_t)64 * VROWS * TP * 2); // 17.0 MB
    float* cs = (float*)alloc((size_t)Tn * 32 * 4);
    float* sn = (float*)alloc((size_t)Tn * 32 * 4);
    u16* yb  = xb; // alias: xb dead after the V^T GEMM; attn writes yb afterwards

    int M = Bsz * Tn; // 8192
    cvt_kernel<<<1024, 256, 0, stream>>>(x, xb, (int)(BTC / 4));
    cvtw_kernel<<<dim3(Cn * Cn / 4 / 256, 4), 256, 0, stream>>>(
        wq, wk, wv, wp, wqb, wkb, wvb, wpb);
    trig_kernel<<<(Tn * 32) / 256, 256, 0, stream>>>(cs, sn);

    // Q,K projections with fused RoPE (+QSCL on Q) -> [B,H,T,D] bf16
    gemm_bt<0><<<dim3(M / 128, Cn / 128, 2), 256, 0, stream>>>(
        xb, wqb, wkb, qr, kr, cs, sn, M, Cn, Cn);

    // V^T = wv * x^T -> vt[bh][d][t] (TP stride)
    gemm_bt<2><<<dim3(Cn / 128, M / 128), 256, 0, stream>>>(
        wvb, xb, nullptr, vt, nullptr, nullptr, nullptr, Cn, M, Cn);

    attn_kernel<<<dim3(512), 256, 0, stream>>>(qr, kr, vt, yb);

    // output projection -> fp32 d_out
    gemm_bt<1><<<dim3(M / 128, Cn / 128), 256, 0, stream>>>(
        yb, wpb, nullptr, d_out, nullptr, nullptr, nullptr, M, Cn, Cn);
}